// Round 6
// baseline (279.425 us; speedup 1.0000x reference)
//
#include <hip/hip_runtime.h>

// Problem constants: B=4, GX=480, GY=360, C_IN=64, C_OUT=32, N=480000
#define GXGY  172800        // GX*GY (multiple of 64: blocks never straddle batch)
#define NSEG  691200        // B*GX*GY
#define NBLK  10800         // NSEG / VPB
#define CIN   64
#define COUT  32
#define VPB   64            // voxels per block
#define PSTR  65            // pooled LDS stride: bank=(lv+...)%32 full-spread, 2-way = free
#define CAP   96            // bucket capacity per block (avg 44, +6 sigma ~ 84)
#define SPILLCAP 8192       // global spill entries (normally 0 used)

// ---------------------------------------------------------------------------
// R9: cut LDS-pipe work (the invariant across R5-R8's identical ~85 us).
//   - decode pass + its barrier DELETED: funkey folded into phase 2 (VALU
//     has headroom at 32%).
//   - sOcc DELETED: occupied <=> first key word != 0 (every fkey > 0).
//   - phase-2 reads grouped in adjacent pairs / 8-k chunks -> ds_read2_b32
//     (64 -> 32 DS instrs) and 4-read batches per lgkm drain.
//   Phase-1 bucket + LDS-atomic scatter-max kept identical to passing R8.
// Workspace: bCnt[10800] + spillCnt + pad + bucket[10800*96] + spill = 4.26MB.
// ---------------------------------------------------------------------------

__device__ __forceinline__ unsigned fkey(float f) {
    unsigned u = __float_as_uint(f);
    return (u & 0x80000000u) ? ~u : (u | 0x80000000u);   // monotone float->uint, >0 always
}
__device__ __forceinline__ float funkey(unsigned k) {
    unsigned u = (k & 0x80000000u) ? (k ^ 0x80000000u) : ~k;
    return __uint_as_float(u);
}

__global__ __launch_bounds__(256) void bin_kernel(
    const int* __restrict__ ind,    // [N,2]
    const int* __restrict__ bidx,   // [N]
    int*       __restrict__ bCnt,   // [NBLK], zeroed
    int*       __restrict__ spillCnt,
    int*       __restrict__ bucket, // [NBLK*CAP]
    int2*      __restrict__ spill,  // [SPILLCAP]
    int N)
{
    int i = blockIdx.x * 256 + threadIdx.x;
    if (i >= N) return;
    int2 xy = ((const int2*)ind)[i];
    int seg = bidx[i] * GXGY + xy.x * 360 + xy.y;
    int blk = seg >> 6;
    int enc = (i << 6) | (seg & 63);          // i < 2^19, local voxel 6 bits
    int pos = atomicAdd(&bCnt[blk], 1);
    if (pos < CAP) {
        bucket[blk * CAP + pos] = enc;
    } else {                                   // statistically unreachable
        int sp = atomicAdd(spillCnt, 1);
        if (sp < SPILLCAP) spill[sp] = make_int2(blk, enc);
    }
}

__global__ __launch_bounds__(256) void pool_compress_kernel(
    const float* __restrict__ fea,      // [N, 64]
    const int*   __restrict__ bCnt,     // [NBLK]
    const int*   __restrict__ spillCnt,
    const int*   __restrict__ bucket,   // [NBLK*CAP]
    const int2*  __restrict__ spill,
    const float* __restrict__ W,        // [64, 32] row-major
    const float* __restrict__ bias,     // [32]
    float*       __restrict__ out)      // [B, 32, GX, GY]
{
    __shared__ __align__(16) unsigned sK[VPB * PSTR];   // 16.25 KB pooled keys
    __shared__ int sIds[CAP];

    int tid = threadIdx.x;
    int blk = blockIdx.x;
    int vbase = blk * VPB;

    // init keys to 0 (below every real fkey) -- vectorized: 4160 words = 1040 int4
    {
        int4 z = make_int4(0, 0, 0, 0);
        #pragma unroll
        for (int j = 0; j < 5; ++j) {
            int idx = tid + j * 256;
            if (idx < (VPB * PSTR) / 4) ((int4*)sK)[idx] = z;
        }
    }

    int nb = min(bCnt[blk], CAP);                    // block-uniform -> s_load
    if (tid < nb) sIds[tid] = bucket[blk * CAP + tid];
    __syncthreads();

    // ---- Phase 1 (identical to passing R8): load-balanced scatter-max ----
    int sg = tid >> 4;        // subgroup 0..15 (16 lanes each)
    int sl = tid & 15;
    for (int r0 = sg; r0 < nb; r0 += 64) {
        // clamped row indices: duplicates re-merge a row into its own voxel
        int r1 = min(r0 + 16, nb - 1);
        int r2 = min(r0 + 32, nb - 1);
        int r3 = min(r0 + 48, nb - 1);
        int e0 = sIds[r0], e1 = sIds[r1], e2 = sIds[r2], e3 = sIds[r3];
        int l0 = e0 & 63, l1 = e1 & 63, l2 = e2 & 63, l3 = e3 & 63;
        // 4 independent float4 loads issue back-to-back (one latency)
        float4 t0 = ((const float4*)(fea + (size_t)(e0 >> 6) * CIN))[sl];
        float4 t1 = ((const float4*)(fea + (size_t)(e1 >> 6) * CIN))[sl];
        float4 t2 = ((const float4*)(fea + (size_t)(e2 >> 6) * CIN))[sl];
        float4 t3 = ((const float4*)(fea + (size_t)(e3 >> 6) * CIN))[sl];

        unsigned* p0 = &sK[l0 * PSTR + sl * 4];
        atomicMax(p0 + 0, fkey(t0.x)); atomicMax(p0 + 1, fkey(t0.y));
        atomicMax(p0 + 2, fkey(t0.z)); atomicMax(p0 + 3, fkey(t0.w));
        unsigned* p1 = &sK[l1 * PSTR + sl * 4];
        atomicMax(p1 + 0, fkey(t1.x)); atomicMax(p1 + 1, fkey(t1.y));
        atomicMax(p1 + 2, fkey(t1.z)); atomicMax(p1 + 3, fkey(t1.w));
        unsigned* p2 = &sK[l2 * PSTR + sl * 4];
        atomicMax(p2 + 0, fkey(t2.x)); atomicMax(p2 + 1, fkey(t2.y));
        atomicMax(p2 + 2, fkey(t2.z)); atomicMax(p2 + 3, fkey(t2.w));
        unsigned* p3 = &sK[l3 * PSTR + sl * 4];
        atomicMax(p3 + 0, fkey(t3.x)); atomicMax(p3 + 1, fkey(t3.y));
        atomicMax(p3 + 2, fkey(t3.z)); atomicMax(p3 + 3, fkey(t3.w));
    }

    // ---- spill merge (normally skipped: nsp == 0) ----
    int nsp = spillCnt[0];
    if (nsp > 0) {
        int ns = min(nsp, SPILLCAP);
        for (int j = 0; j < ns; ++j) {
            int2 e = spill[j];                        // broadcast load
            if (e.x == blk && tid < 16) {
                int lv = e.y & 63;
                float4 t = ((const float4*)(fea + (size_t)(e.y >> 6) * CIN))[tid];
                unsigned* p = &sK[lv * PSTR + tid * 4];
                atomicMax(p + 0, fkey(t.x)); atomicMax(p + 1, fkey(t.y));
                atomicMax(p + 2, fkey(t.z)); atomicMax(p + 3, fkey(t.w));
            }
        }
    }
    __syncthreads();

    // ---- Phase 2: 64x8 matvec; keys decoded inline; occ = (key0 != 0) ----
    int wid  = tid >> 6;
    int lane = tid & 63;
    int lv = lane;                                   // voxel within block
    int g  = __builtin_amdgcn_readfirstlane(wid);    // wave-uniform SGPR
    int b  = vbase / GXGY;                           // uniform per block
    int rem = vbase - b * GXGY + lv;

    const float* Wg = W + g * 8;
    const float* bg = bias + g * 8;

    const unsigned* row = &sK[lv * PSTR];
    unsigned occk = row[0];                          // fkey>0 always => occ test

    float res[8];
    if (occk != 0u) {
        float acc[8];
        #pragma unroll
        for (int c = 0; c < 8; ++c) acc[c] = bg[c];
        // 8 chunks of 8 k-values: adjacent-pair reads merge to ds_read2_b32,
        // 4 DS reads batch per drain instead of per-k interleave.
        #pragma unroll
        for (int m = 0; m < 8; ++m) {
            unsigned kk0 = row[m * 8 + 0], kk1 = row[m * 8 + 1];
            unsigned kk2 = row[m * 8 + 2], kk3 = row[m * 8 + 3];
            unsigned kk4 = row[m * 8 + 4], kk5 = row[m * 8 + 5];
            unsigned kk6 = row[m * 8 + 6], kk7 = row[m * 8 + 7];
            float p0 = funkey(kk0), p1 = funkey(kk1);
            float p2 = funkey(kk2), p3 = funkey(kk3);
            float p4 = funkey(kk4), p5 = funkey(kk5);
            float p6 = funkey(kk6), p7 = funkey(kk7);
            const float* Wm = Wg + (m * 8) * COUT;
            #pragma unroll
            for (int c = 0; c < 8; ++c) {
                float a = acc[c];
                a = fmaf(p0, Wm[0 * COUT + c], a);
                a = fmaf(p1, Wm[1 * COUT + c], a);
                a = fmaf(p2, Wm[2 * COUT + c], a);
                a = fmaf(p3, Wm[3 * COUT + c], a);
                a = fmaf(p4, Wm[4 * COUT + c], a);
                a = fmaf(p5, Wm[5 * COUT + c], a);
                a = fmaf(p6, Wm[6 * COUT + c], a);
                a = fmaf(p7, Wm[7 * COUT + c], a);
                acc[c] = a;
            }
        }
        #pragma unroll
        for (int c = 0; c < 8; ++c) res[c] = fmaxf(acc[c], 0.0f);
    } else {
        #pragma unroll
        for (int c = 0; c < 8; ++c) res[c] = 0.0f;
    }

    float* op = out + (size_t)b * COUT * GXGY + (size_t)g * 8 * GXGY + rem;
    #pragma unroll
    for (int c = 0; c < 8; ++c) op[c * GXGY] = res[c];
}

extern "C" void kernel_launch(void* const* d_in, const int* in_sizes, int n_in,
                              void* d_out, int out_size, void* d_ws, size_t ws_size,
                              hipStream_t stream)
{
    const float* fea  = (const float*)d_in[0];
    const int*   ind  = (const int*)d_in[1];
    const int*   bidx = (const int*)d_in[2];
    const float* W    = (const float*)d_in[3];
    const float* bias = (const float*)d_in[4];
    float*       out  = (float*)d_out;

    int N = in_sizes[0] / CIN;  // 480000

    // ws layout (ints): bCnt[NBLK] | spillCnt | pad to 10816 | bucket[NBLK*CAP] | spill[2*SPILLCAP]
    int* bCnt     = (int*)d_ws;
    int* spillCnt = bCnt + NBLK;
    int* bucket   = bCnt + 10816;                 // 16-aligned start
    int2* spill   = (int2*)(bucket + NBLK * CAP); // 8B-aligned (even int offset)

    hipMemsetAsync(bCnt, 0, 10816 * sizeof(int), stream);   // bCnt + spillCnt + pad
    bin_kernel<<<(N + 255) / 256, 256, 0, stream>>>(ind, bidx, bCnt, spillCnt,
                                                    bucket, spill, N);
    pool_compress_kernel<<<NBLK, 256, 0, stream>>>(fea, bCnt, spillCnt, bucket,
                                                   spill, W, bias, out);
}

// Round 7
// 278.432 us; speedup vs baseline: 1.0036x; 1.0036x over previous
//
#include <hip/hip_runtime.h>

// Problem constants: B=4, GX=480, GY=360, C_IN=64, C_OUT=32, N=480000
#define GXGY  172800        // GX*GY (multiple of 64: blocks never straddle batch)
#define NSEG  691200        // B*GX*GY
#define NBLK  10800         // NSEG / VPB
#define CIN   64
#define COUT  32
#define VPB   64            // voxels per tile
#define PSTR  65            // pooled LDS stride: bank=(lv+4sl)%32 -> 2-way = free
#define CAP   96            // bucket capacity per tile (avg 44, +6 sigma ~ 84)
#define SPILLCAP 8192       // global spill entries (normally 0 used)
#define GRID  2048          // persistent blocks: 8 per CU, ~5.3 tiles each

// ---------------------------------------------------------------------------
// R10: break lockstep. R9's post-mortem: wave-serial time IS the duration
//   (VALU adds show 1:1; LDS halving shows 0) -> all waves stall on the same
//   phase at the same time. Fix: persistent blocks, software-pipelined tiles:
//   tile i+1's id-staging and fea-gather issue BEFORE tile i's matvec, so
//   gather latency hides under phase-2 VALU. Phase-1 atomics and phase-2
//   numerics unchanged from passing R8/R9.
// Workspace: bCnt[10800] + spillCnt + pad + bucket[10800*96] + spill = 4.26MB.
// ---------------------------------------------------------------------------

__device__ __forceinline__ unsigned fkey(float f) {
    unsigned u = __float_as_uint(f);
    return (u & 0x80000000u) ? ~u : (u | 0x80000000u);   // monotone, >0 for finite
}
__device__ __forceinline__ float funkey(unsigned k) {
    unsigned u = (k & 0x80000000u) ? (k ^ 0x80000000u) : ~k;
    return __uint_as_float(u);
}

__global__ __launch_bounds__(256) void bin_kernel(
    const int* __restrict__ ind,    // [N,2]
    const int* __restrict__ bidx,   // [N]
    int*       __restrict__ bCnt,   // [NBLK], zeroed
    int*       __restrict__ spillCnt,
    int*       __restrict__ bucket, // [NBLK*CAP]
    int2*      __restrict__ spill,  // [SPILLCAP]
    int N)
{
    int i = blockIdx.x * 256 + threadIdx.x;
    if (i >= N) return;
    int2 xy = ((const int2*)ind)[i];
    int seg = bidx[i] * GXGY + xy.x * 360 + xy.y;
    int blk = seg >> 6;
    int enc = (i << 6) | (seg & 63);          // i < 2^19, local voxel 6 bits
    int pos = atomicAdd(&bCnt[blk], 1);
    if (pos < CAP) {
        bucket[blk * CAP + pos] = enc;
    } else {                                   // statistically unreachable
        int sp = atomicAdd(spillCnt, 1);
        if (sp < SPILLCAP) spill[sp] = make_int2(blk, enc);
    }
}

__global__ __launch_bounds__(256) void pool_compress_kernel(
    const float* __restrict__ fea,      // [N, 64]
    const int*   __restrict__ bCnt,     // [NBLK]
    const int*   __restrict__ spillCnt,
    const int*   __restrict__ bucket,   // [NBLK*CAP]
    const int2*  __restrict__ spill,
    const float* __restrict__ W,        // [64, 32] row-major
    const float* __restrict__ bias,     // [32]
    float*       __restrict__ out)      // [B, 32, GX, GY]
{
    __shared__ __align__(16) unsigned sK[VPB * PSTR];   // 16.25 KB pooled keys
    __shared__ int sIds[2][CAP];

    int tid  = threadIdx.x;
    int sg   = tid >> 4;       // subgroup 0..15
    int sl   = tid & 15;       // lane in subgroup
    int wid  = tid >> 6;
    int lane = tid & 63;
    int g    = __builtin_amdgcn_readfirstlane(wid);  // wave-uniform cout group
    const float* Wg = W + g * 8;
    const float* bg = bias + g * 8;
    int nsp = spillCnt[0];     // constant after bin; normally 0

    // ---- prologue: zero sK, stage tile0 ids, peek tile0+GRID count ----
    {
        int4 z = make_int4(0, 0, 0, 0);
        #pragma unroll
        for (int j = 0; j < 5; ++j) {
            int idx = tid + j * 256;
            if (idx < (VPB * PSTR) / 4) ((int4*)sK)[idx] = z;
        }
    }
    int tile   = blockIdx.x;
    int nb_cur = min(bCnt[tile], CAP);
    if (tid < nb_cur) sIds[0][tid] = bucket[tile * CAP + tid];
    int nxt    = tile + GRID;
    int nb_nxt = (nxt < NBLK) ? min(bCnt[nxt], CAP) : 0;
    __syncthreads();

    // issue gather for tile0 (4 rows per subgroup, clamped = idempotent)
    int buf = 0;
    int e0 = 0, e1 = 0, e2 = 0, e3 = 0;
    float4 t0, t1, t2, t3;
    if (nb_cur > 0) {
        int nbm = nb_cur - 1;
        e0 = sIds[0][min(sg,      nbm)];
        e1 = sIds[0][min(sg + 16, nbm)];
        e2 = sIds[0][min(sg + 32, nbm)];
        e3 = sIds[0][min(sg + 48, nbm)];
        t0 = ((const float4*)(fea + (size_t)(e0 >> 6) * CIN))[sl];
        t1 = ((const float4*)(fea + (size_t)(e1 >> 6) * CIN))[sl];
        t2 = ((const float4*)(fea + (size_t)(e2 >> 6) * CIN))[sl];
        t3 = ((const float4*)(fea + (size_t)(e3 >> 6) * CIN))[sl];
    }

    while (tile < NBLK) {
        // ---- B: merge current tile (gather regs in flight since last iter) ----
        if (nb_cur > 0) {
            int l0 = e0 & 63, l1 = e1 & 63, l2 = e2 & 63, l3 = e3 & 63;
            unsigned* p0 = &sK[l0 * PSTR + sl * 4];
            atomicMax(p0 + 0, fkey(t0.x)); atomicMax(p0 + 1, fkey(t0.y));
            atomicMax(p0 + 2, fkey(t0.z)); atomicMax(p0 + 3, fkey(t0.w));
            unsigned* p1 = &sK[l1 * PSTR + sl * 4];
            atomicMax(p1 + 0, fkey(t1.x)); atomicMax(p1 + 1, fkey(t1.y));
            atomicMax(p1 + 2, fkey(t1.z)); atomicMax(p1 + 3, fkey(t1.w));
            unsigned* p2 = &sK[l2 * PSTR + sl * 4];
            atomicMax(p2 + 0, fkey(t2.x)); atomicMax(p2 + 1, fkey(t2.y));
            atomicMax(p2 + 2, fkey(t2.z)); atomicMax(p2 + 3, fkey(t2.w));
            unsigned* p3 = &sK[l3 * PSTR + sl * 4];
            atomicMax(p3 + 0, fkey(t3.x)); atomicMax(p3 + 1, fkey(t3.y));
            atomicMax(p3 + 2, fkey(t3.z)); atomicMax(p3 + 3, fkey(t3.w));
            // rare overflow rows 64..nb_cur-1 (P ~ 0.2% of tiles)
            for (int r = sg + 64; r < nb_cur; r += 16) {
                int e = sIds[buf][r];
                int l = e & 63;
                float4 t = ((const float4*)(fea + (size_t)(e >> 6) * CIN))[sl];
                unsigned* p = &sK[l * PSTR + sl * 4];
                atomicMax(p + 0, fkey(t.x)); atomicMax(p + 1, fkey(t.y));
                atomicMax(p + 2, fkey(t.z)); atomicMax(p + 3, fkey(t.w));
            }
        }
        // ---- spill merge for current tile (normally nsp == 0) ----
        if (nsp > 0) {
            int ns = min(nsp, SPILLCAP);
            for (int j = 0; j < ns; ++j) {
                int2 e = spill[j];
                if (e.x == tile && tid < 16) {
                    int lv = e.y & 63;
                    float4 t = ((const float4*)(fea + (size_t)(e.y >> 6) * CIN))[tid];
                    unsigned* p = &sK[lv * PSTR + tid * 4];
                    atomicMax(p + 0, fkey(t.x)); atomicMax(p + 1, fkey(t.y));
                    atomicMax(p + 2, fkey(t.z)); atomicMax(p + 3, fkey(t.w));
                }
            }
        }
        // ---- C: stage next tile's ids; peek tile+2*GRID count ----
        if (tid < nb_nxt) sIds[buf ^ 1][tid] = bucket[nxt * CAP + tid];
        int nxt2    = nxt + GRID;
        int nb_nxt2 = (nxt2 < NBLK) ? min(bCnt[nxt2], CAP) : 0;
        __syncthreads();   // atomics done + sIds[buf^1] visible

        // ---- D: issue gather for next tile (latency hides under phase 2) ----
        int ne0 = 0, ne1 = 0, ne2 = 0, ne3 = 0;
        float4 nt0, nt1, nt2, nt3;
        if (nb_nxt > 0) {
            int nbm = nb_nxt - 1;
            int bn  = buf ^ 1;
            ne0 = sIds[bn][min(sg,      nbm)];
            ne1 = sIds[bn][min(sg + 16, nbm)];
            ne2 = sIds[bn][min(sg + 32, nbm)];
            ne3 = sIds[bn][min(sg + 48, nbm)];
            nt0 = ((const float4*)(fea + (size_t)(ne0 >> 6) * CIN))[sl];
            nt1 = ((const float4*)(fea + (size_t)(ne1 >> 6) * CIN))[sl];
            nt2 = ((const float4*)(fea + (size_t)(ne2 >> 6) * CIN))[sl];
            nt3 = ((const float4*)(fea + (size_t)(ne3 >> 6) * CIN))[sl];
        }

        // ---- E: phase 2 on current tile (R9 body, inline decode) ----
        {
            int vbase = tile * VPB;
            int b   = vbase / GXGY;
            int rem = vbase - b * GXGY + lane;
            const unsigned* row = &sK[lane * PSTR];
            unsigned occk = row[0];                  // fkey>0 always => occ test
            float res[8];
            if (occk != 0u) {
                float acc[8];
                #pragma unroll
                for (int c = 0; c < 8; ++c) acc[c] = bg[c];
                #pragma unroll
                for (int m = 0; m < 8; ++m) {
                    unsigned kk0 = row[m * 8 + 0], kk1 = row[m * 8 + 1];
                    unsigned kk2 = row[m * 8 + 2], kk3 = row[m * 8 + 3];
                    unsigned kk4 = row[m * 8 + 4], kk5 = row[m * 8 + 5];
                    unsigned kk6 = row[m * 8 + 6], kk7 = row[m * 8 + 7];
                    float p0 = funkey(kk0), p1 = funkey(kk1);
                    float p2 = funkey(kk2), p3 = funkey(kk3);
                    float p4 = funkey(kk4), p5 = funkey(kk5);
                    float p6 = funkey(kk6), p7 = funkey(kk7);
                    const float* Wm = Wg + (m * 8) * COUT;
                    #pragma unroll
                    for (int c = 0; c < 8; ++c) {
                        float a = acc[c];
                        a = fmaf(p0, Wm[0 * COUT + c], a);
                        a = fmaf(p1, Wm[1 * COUT + c], a);
                        a = fmaf(p2, Wm[2 * COUT + c], a);
                        a = fmaf(p3, Wm[3 * COUT + c], a);
                        a = fmaf(p4, Wm[4 * COUT + c], a);
                        a = fmaf(p5, Wm[5 * COUT + c], a);
                        a = fmaf(p6, Wm[6 * COUT + c], a);
                        a = fmaf(p7, Wm[7 * COUT + c], a);
                        acc[c] = a;
                    }
                }
                #pragma unroll
                for (int c = 0; c < 8; ++c) res[c] = fmaxf(acc[c], 0.0f);
            } else {
                #pragma unroll
                for (int c = 0; c < 8; ++c) res[c] = 0.0f;
            }
            float* op = out + (size_t)b * COUT * GXGY + (size_t)g * 8 * GXGY + rem;
            #pragma unroll
            for (int c = 0; c < 8; ++c) op[c * GXGY] = res[c];
        }
        __syncthreads();   // all phase-2 LDS reads complete

        // ---- G: zero sK for the next tile ----
        {
            int4 z = make_int4(0, 0, 0, 0);
            #pragma unroll
            for (int j = 0; j < 5; ++j) {
                int idx = tid + j * 256;
                if (idx < (VPB * PSTR) / 4) ((int4*)sK)[idx] = z;
            }
        }
        __syncthreads();   // zero visible before next iteration's atomics

        // ---- rotate pipeline state ----
        tile = nxt; nxt = nxt2;
        nb_cur = nb_nxt; nb_nxt = nb_nxt2;
        e0 = ne0; e1 = ne1; e2 = ne2; e3 = ne3;
        t0 = nt0; t1 = nt1; t2 = nt2; t3 = nt3;
        buf ^= 1;
    }
}

extern "C" void kernel_launch(void* const* d_in, const int* in_sizes, int n_in,
                              void* d_out, int out_size, void* d_ws, size_t ws_size,
                              hipStream_t stream)
{
    const float* fea  = (const float*)d_in[0];
    const int*   ind  = (const int*)d_in[1];
    const int*   bidx = (const int*)d_in[2];
    const float* W    = (const float*)d_in[3];
    const float* bias = (const float*)d_in[4];
    float*       out  = (float*)d_out;

    int N = in_sizes[0] / CIN;  // 480000

    // ws layout (ints): bCnt[NBLK] | spillCnt | pad to 10816 | bucket[NBLK*CAP] | spill[2*SPILLCAP]
    int* bCnt     = (int*)d_ws;
    int* spillCnt = bCnt + NBLK;
    int* bucket   = bCnt + 10816;                 // 16-aligned start
    int2* spill   = (int2*)(bucket + NBLK * CAP); // 8B-aligned (even int offset)

    hipMemsetAsync(bCnt, 0, 10816 * sizeof(int), stream);   // bCnt + spillCnt + pad
    bin_kernel<<<(N + 255) / 256, 256, 0, stream>>>(ind, bidx, bCnt, spillCnt,
                                                    bucket, spill, N);
    pool_compress_kernel<<<GRID, 256, 0, stream>>>(fea, bCnt, spillCnt, bucket,
                                                   spill, W, bias, out);
}

// Round 8
// 271.203 us; speedup vs baseline: 1.0303x; 1.0267x over previous
//
#include <hip/hip_runtime.h>

// Problem constants: B=4, GX=480, GY=360, C_IN=64, C_OUT=32, N=480000
#define GXGY  172800        // GX*GY; GXGY/VPB = 1350 -> blocks never straddle batch
#define NSEG  691200        // B*GX*GY
#define CIN   64
#define COUT  32
#define VPB   128           // voxels per block (R11: doubled)
#define NBLK  5400          // NSEG / VPB
#define PSTR  65            // pooled LDS stride: 65 = 1 mod 32 -> lane->bank 2-way = free
#define CAP   160           // bucket capacity per tile (avg 89, +7.5 sigma)
#define SPILLCAP 8192       // global spill entries (normally 0 used)

// ---------------------------------------------------------------------------
// R11: occupancy attack. dur x occ == ~50 us*occ across R5-R10 (4 different
//   algorithms) => throughput scales with resident waves; resources permit 8
//   blocks/CU but HW sits at ~4.6 blocks/CU even with persistent 8/CU grid.
//   => pack more waves per workgroup: 512-thread blocks, 128-voxel tiles.
//   4 resident blocks x 8 waves = 32 waves/CU = 100% (fits the ~4.6 cap).
//   Algorithm byte-identical to R8/R9: bucket -> LDS atomic scatter-max ->
//   inline-decode matvec; 2 barriers; non-persistent grid.
// Workspace: bCnt[5400]+spillCnt+pad+bucket[5400*160]+spill = ~3.5 MB.
// ---------------------------------------------------------------------------

__device__ __forceinline__ unsigned fkey(float f) {
    unsigned u = __float_as_uint(f);
    return (u & 0x80000000u) ? ~u : (u | 0x80000000u);   // monotone, >0 for finite
}
__device__ __forceinline__ float funkey(unsigned k) {
    unsigned u = (k & 0x80000000u) ? (k ^ 0x80000000u) : ~k;
    return __uint_as_float(u);
}

__global__ __launch_bounds__(256) void bin_kernel(
    const int* __restrict__ ind,    // [N,2]
    const int* __restrict__ bidx,   // [N]
    int*       __restrict__ bCnt,   // [NBLK], zeroed
    int*       __restrict__ spillCnt,
    int*       __restrict__ bucket, // [NBLK*CAP]
    int2*      __restrict__ spill,  // [SPILLCAP]
    int N)
{
    int i = blockIdx.x * 256 + threadIdx.x;
    if (i >= N) return;
    int2 xy = ((const int2*)ind)[i];
    int seg = bidx[i] * GXGY + xy.x * 360 + xy.y;
    int blk = seg >> 7;                       // 128-voxel tiles
    int enc = (i << 7) | (seg & 127);         // i < 2^19, local voxel 7 bits
    int pos = atomicAdd(&bCnt[blk], 1);
    if (pos < CAP) {
        bucket[blk * CAP + pos] = enc;
    } else {                                   // statistically unreachable
        int sp = atomicAdd(spillCnt, 1);
        if (sp < SPILLCAP) spill[sp] = make_int2(blk, enc);
    }
}

__global__ __launch_bounds__(512) void pool_compress_kernel(
    const float* __restrict__ fea,      // [N, 64]
    const int*   __restrict__ bCnt,     // [NBLK]
    const int*   __restrict__ spillCnt,
    const int*   __restrict__ bucket,   // [NBLK*CAP]
    const int2*  __restrict__ spill,
    const float* __restrict__ W,        // [64, 32] row-major
    const float* __restrict__ bias,     // [32]
    float*       __restrict__ out)      // [B, 32, GX, GY]
{
    __shared__ __align__(16) unsigned sK[VPB * PSTR];   // 32.5 KB pooled keys
    __shared__ int sIds[CAP];

    int tid = threadIdx.x;
    int blk = blockIdx.x;
    int vbase = blk * VPB;

    // init keys to 0 (below every real fkey): 8320 words = 2080 int4
    {
        int4 z = make_int4(0, 0, 0, 0);
        #pragma unroll
        for (int j = 0; j < 5; ++j) {
            int idx = tid + j * 512;
            if (idx < (VPB * PSTR) / 4) ((int4*)sK)[idx] = z;
        }
    }

    int nb = min(bCnt[blk], CAP);                    // block-uniform -> s_load
    if (tid < nb) sIds[tid] = bucket[blk * CAP + tid];
    __syncthreads();

    // ---- Phase 1: load-balanced scatter-max, 4-deep batched loads ----
    int sg = tid >> 4;        // subgroup 0..31 (16 lanes each)
    int sl = tid & 15;
    if (nb > 0) {
        int nbm = nb - 1;
        // clamped row indices: duplicates re-merge a row into its own voxel
        int e0 = sIds[min(sg,       nbm)];
        int e1 = sIds[min(sg + 32,  nbm)];
        int e2 = sIds[min(sg + 64,  nbm)];
        int e3 = sIds[min(sg + 96,  nbm)];
        int l0 = e0 & 127, l1 = e1 & 127, l2 = e2 & 127, l3 = e3 & 127;
        // 4 independent float4 loads issue back-to-back (one latency)
        float4 t0 = ((const float4*)(fea + (size_t)(e0 >> 7) * CIN))[sl];
        float4 t1 = ((const float4*)(fea + (size_t)(e1 >> 7) * CIN))[sl];
        float4 t2 = ((const float4*)(fea + (size_t)(e2 >> 7) * CIN))[sl];
        float4 t3 = ((const float4*)(fea + (size_t)(e3 >> 7) * CIN))[sl];

        unsigned* p0 = &sK[l0 * PSTR + sl * 4];
        atomicMax(p0 + 0, fkey(t0.x)); atomicMax(p0 + 1, fkey(t0.y));
        atomicMax(p0 + 2, fkey(t0.z)); atomicMax(p0 + 3, fkey(t0.w));
        unsigned* p1 = &sK[l1 * PSTR + sl * 4];
        atomicMax(p1 + 0, fkey(t1.x)); atomicMax(p1 + 1, fkey(t1.y));
        atomicMax(p1 + 2, fkey(t1.z)); atomicMax(p1 + 3, fkey(t1.w));
        unsigned* p2 = &sK[l2 * PSTR + sl * 4];
        atomicMax(p2 + 0, fkey(t2.x)); atomicMax(p2 + 1, fkey(t2.y));
        atomicMax(p2 + 2, fkey(t2.z)); atomicMax(p2 + 3, fkey(t2.w));
        unsigned* p3 = &sK[l3 * PSTR + sl * 4];
        atomicMax(p3 + 0, fkey(t3.x)); atomicMax(p3 + 1, fkey(t3.y));
        atomicMax(p3 + 2, fkey(t3.z)); atomicMax(p3 + 3, fkey(t3.w));
        // rare overflow rows 128..nb-1
        for (int r = sg + 128; r < nb; r += 32) {
            int e = sIds[r];
            int l = e & 127;
            float4 t = ((const float4*)(fea + (size_t)(e >> 7) * CIN))[sl];
            unsigned* p = &sK[l * PSTR + sl * 4];
            atomicMax(p + 0, fkey(t.x)); atomicMax(p + 1, fkey(t.y));
            atomicMax(p + 2, fkey(t.z)); atomicMax(p + 3, fkey(t.w));
        }
    }

    // ---- spill merge (normally skipped: nsp == 0) ----
    int nsp = spillCnt[0];
    if (nsp > 0) {
        int ns = min(nsp, SPILLCAP);
        for (int j = 0; j < ns; ++j) {
            int2 e = spill[j];                        // broadcast load
            if (e.x == blk && tid < 16) {
                int lv = e.y & 127;
                float4 t = ((const float4*)(fea + (size_t)(e.y >> 7) * CIN))[tid];
                unsigned* p = &sK[lv * PSTR + tid * 4];
                atomicMax(p + 0, fkey(t.x)); atomicMax(p + 1, fkey(t.y));
                atomicMax(p + 2, fkey(t.z)); atomicMax(p + 3, fkey(t.w));
            }
        }
    }
    __syncthreads();

    // ---- Phase 2: 128x8 matvec; keys decoded inline; occ = (key0 != 0) ----
    int g  = __builtin_amdgcn_readfirstlane(tid >> 7);   // cout group 0..3, wave-uniform
    int lv = tid & 127;                                  // voxel within tile
    int b  = vbase / GXGY;                               // uniform per block
    int rem = vbase - b * GXGY + lv;

    const float* Wg = W + g * 8;
    const float* bg = bias + g * 8;

    const unsigned* row = &sK[lv * PSTR];
    unsigned occk = row[0];                              // fkey>0 always => occ test

    float res[8];
    if (occk != 0u) {
        float acc[8];
        #pragma unroll
        for (int c = 0; c < 8; ++c) acc[c] = bg[c];
        #pragma unroll
        for (int m = 0; m < 8; ++m) {
            unsigned kk0 = row[m * 8 + 0], kk1 = row[m * 8 + 1];
            unsigned kk2 = row[m * 8 + 2], kk3 = row[m * 8 + 3];
            unsigned kk4 = row[m * 8 + 4], kk5 = row[m * 8 + 5];
            unsigned kk6 = row[m * 8 + 6], kk7 = row[m * 8 + 7];
            float p0 = funkey(kk0), p1 = funkey(kk1);
            float p2 = funkey(kk2), p3 = funkey(kk3);
            float p4 = funkey(kk4), p5 = funkey(kk5);
            float p6 = funkey(kk6), p7 = funkey(kk7);
            const float* Wm = Wg + (m * 8) * COUT;
            #pragma unroll
            for (int c = 0; c < 8; ++c) {
                float a = acc[c];
                a = fmaf(p0, Wm[0 * COUT + c], a);
                a = fmaf(p1, Wm[1 * COUT + c], a);
                a = fmaf(p2, Wm[2 * COUT + c], a);
                a = fmaf(p3, Wm[3 * COUT + c], a);
                a = fmaf(p4, Wm[4 * COUT + c], a);
                a = fmaf(p5, Wm[5 * COUT + c], a);
                a = fmaf(p6, Wm[6 * COUT + c], a);
                a = fmaf(p7, Wm[7 * COUT + c], a);
                acc[c] = a;
            }
        }
        #pragma unroll
        for (int c = 0; c < 8; ++c) res[c] = fmaxf(acc[c], 0.0f);
    } else {
        #pragma unroll
        for (int c = 0; c < 8; ++c) res[c] = 0.0f;
    }

    float* op = out + (size_t)b * COUT * GXGY + (size_t)g * 8 * GXGY + rem;
    #pragma unroll
    for (int c = 0; c < 8; ++c) op[c * GXGY] = res[c];
}

extern "C" void kernel_launch(void* const* d_in, const int* in_sizes, int n_in,
                              void* d_out, int out_size, void* d_ws, size_t ws_size,
                              hipStream_t stream)
{
    const float* fea  = (const float*)d_in[0];
    const int*   ind  = (const int*)d_in[1];
    const int*   bidx = (const int*)d_in[2];
    const float* W    = (const float*)d_in[3];
    const float* bias = (const float*)d_in[4];
    float*       out  = (float*)d_out;

    int N = in_sizes[0] / CIN;  // 480000

    // ws layout (ints): bCnt[NBLK] | spillCnt | pad to 5408 | bucket[NBLK*CAP] | spill[2*SPILLCAP]
    int* bCnt     = (int*)d_ws;
    int* spillCnt = bCnt + NBLK;
    int* bucket   = bCnt + 5408;                  // 16-aligned start
    int2* spill   = (int2*)(bucket + NBLK * CAP); // 8B-aligned (even int offset)

    hipMemsetAsync(bCnt, 0, 5408 * sizeof(int), stream);    // bCnt + spillCnt + pad
    bin_kernel<<<(N + 255) / 256, 256, 0, stream>>>(ind, bidx, bCnt, spillCnt,
                                                    bucket, spill, N);
    pool_compress_kernel<<<NBLK, 512, 0, stream>>>(fea, bCnt, spillCnt, bucket,
                                                   spill, W, bias, out);
}